// Round 1
// baseline (206.198 us; speedup 1.0000x reference)
//
#include <hip/hip_runtime.h>

#define Bdim 16
#define Ndim 1024
#define DIN  128
#define Hh   4
#define Dd   32
#define HD   128   // Hh*Dd

#define TI   32
#define TJ   32
#define IPAD 40    // padded TI for sh_p (16B-aligned rows, spreads banks)

// ---------------- Kernel A: h = x@W + b ; e_i, e_j head dots ----------------
__global__ __launch_bounds__(256) void proj_kernel(
    const float* __restrict__ x, const float* __restrict__ W,
    const float* __restrict__ bias, const float* __restrict__ a,
    float* __restrict__ h, float* __restrict__ ei, float* __restrict__ ej)
{
    __shared__ float sx[16][DIN];
    const int t = threadIdx.x;
    const int col = t & 127;
    const int half = t >> 7;
    const int row_base = blockIdx.x * 16;

    // stage 16 rows of x: 512 float4, 2 per thread, coalesced
    {
        const float4* xs = (const float4*)(x + (size_t)row_base * DIN);
        float4* sxv = (float4*)&sx[0][0];
        #pragma unroll
        for (int r = 0; r < 2; ++r) {
            int idx = r * 256 + t;
            sxv[idx] = xs[idx];
        }
    }
    __syncthreads();

    float acc[8];
    const float bv = bias[col];
    #pragma unroll
    for (int rr = 0; rr < 8; ++rr) acc[rr] = bv;

    // each thread: 8 rows x 1 col; W value reused 8x
    #pragma unroll 4
    for (int k4 = 0; k4 < DIN / 4; ++k4) {
        float w0 = W[(k4 * 4 + 0) * HD + col];
        float w1 = W[(k4 * 4 + 1) * HD + col];
        float w2 = W[(k4 * 4 + 2) * HD + col];
        float w3 = W[(k4 * 4 + 3) * HD + col];
        #pragma unroll
        for (int rr = 0; rr < 8; ++rr) {
            float4 xv = *(const float4*)&sx[half * 8 + rr][k4 * 4];
            acc[rr] = fmaf(xv.x, w0, acc[rr]);
            acc[rr] = fmaf(xv.y, w1, acc[rr]);
            acc[rr] = fmaf(xv.z, w2, acc[rr]);
            acc[rr] = fmaf(xv.w, w3, acc[rr]);
        }
    }

    const int d = col & 31;
    const int head = col >> 5;
    const float av_i = a[d];
    const float av_j = a[Dd + d];
    #pragma unroll
    for (int rr = 0; rr < 8; ++rr) {
        int row = row_base + half * 8 + rr;
        h[(size_t)row * HD + col] = acc[rr];
        float vi = acc[rr] * av_i;
        float vj = acc[rr] * av_j;
        #pragma unroll
        for (int off = 16; off > 0; off >>= 1) {
            vi += __shfl_down(vi, off, 32);
            vj += __shfl_down(vj, off, 32);
        }
        if (d == 0) {
            ei[row * Hh + head] = vi;
            ej[row * Hh + head] = vj;
        }
    }
}

// ---------------- Kernel C: fused masked softmax + PV ----------------
__global__ __launch_bounds__(256) void gat_kernel(
    const int* __restrict__ adj, const float* __restrict__ h,
    const float* __restrict__ ei, const float* __restrict__ ej,
    float* __restrict__ out)
{
    __shared__ float sh_h[TJ][HD];           // 16 KB
    __shared__ float sh_p[TJ][Hh][IPAD];     // 20 KB
    __shared__ int   sh_adj[TI][TJ + 1];     // 4.2 KB (pad breaks 32-stride)
    __shared__ float sh_ej[TJ][Hh];          // 0.5 KB
    __shared__ float sh_den[2][Hh][TI];      // 1 KB

    const int t = threadIdx.x;
    const int b = blockIdx.y;
    const int i_base = blockIdx.x * TI;

    // phase-2 persistent mapping: thread -> (i, h, j-half)
    const int p_i  = t & 31;
    const int p_h  = (t >> 5) & 3;
    const int p_jh = t >> 7;
    const float my_ei = ei[(b * Ndim + i_base + p_i) * Hh + p_h];
    float den = 0.f;

    // phase-3 mapping: thread -> (4 cols, 4 rows)
    const int c4 = t & 31;       // col group: cols c4*4..+3
    const int i_sub = t >> 5;    // row group: i_sub*4..+3
    const int o_h = c4 >> 3;     // head of this col group
    float num[4][4];
    #pragma unroll
    for (int ii = 0; ii < 4; ++ii)
        #pragma unroll
        for (int cc = 0; cc < 4; ++cc) num[ii][cc] = 0.f;

    const float* hb = h + (size_t)b * Ndim * HD;
    const int* adjb = adj + ((size_t)b * Ndim + i_base) * Ndim;

    for (int j_base = 0; j_base < Ndim; j_base += TJ) {
        // ---- stage h tile (32x128 f32 = 1024 float4, 4/thread, coalesced)
        #pragma unroll
        for (int r = 0; r < 4; ++r) {
            int idx = r * 256 + t;
            int jr = idx >> 5, q = idx & 31;
            float4 v = *(const float4*)(hb + (j_base + jr) * HD + q * 4);
            *(float4*)&sh_h[jr][q * 4] = v;
        }
        // ---- stage adj tile (32x32 int = 256 int4, 1/thread)
        {
            int ir = t >> 3, q = t & 7;
            int4 v = *(const int4*)(adjb + ir * Ndim + j_base + q * 4);
            sh_adj[ir][q * 4 + 0] = v.x;
            sh_adj[ir][q * 4 + 1] = v.y;
            sh_adj[ir][q * 4 + 2] = v.z;
            sh_adj[ir][q * 4 + 3] = v.w;
        }
        // ---- stage e_j tile
        if (t < 128) {
            sh_ej[t >> 2][t & 3] =
                ej[(b * Ndim + j_base + (t >> 2)) * Hh + (t & 3)];
        }
        __syncthreads();

        // ---- phase 2: p = adj ? exp(leaky(ei+ej)) : 0, once per (i,j,h)
        #pragma unroll
        for (int jj = 0; jj < 16; ++jj) {
            int j = p_jh * 16 + jj;
            float e = my_ei + sh_ej[j][p_h];
            e = fmaf(fminf(e, 0.f), 0.2f, fmaxf(e, 0.f));  // leaky 0.2
            float p = (sh_adj[p_i][j] > 0) ? __expf(e) : 0.f;
            den += p;
            sh_p[j][p_h][p_i] = p;
        }
        __syncthreads();

        // ---- phase 3: 4x4 register-blocked accumulation
        #pragma unroll 4
        for (int j = 0; j < TJ; ++j) {
            float4 hv = *(const float4*)&sh_h[j][c4 * 4];
            float4 pv = *(const float4*)&sh_p[j][o_h][i_sub * 4];
            float hvf[4] = {hv.x, hv.y, hv.z, hv.w};
            float pvf[4] = {pv.x, pv.y, pv.z, pv.w};
            #pragma unroll
            for (int ii = 0; ii < 4; ++ii)
                #pragma unroll
                for (int cc = 0; cc < 4; ++cc)
                    num[ii][cc] = fmaf(pvf[ii], hvf[cc], num[ii][cc]);
        }
        __syncthreads();
    }

    // ---- combine den halves, normalize, store
    sh_den[p_jh][p_h][p_i] = den;
    __syncthreads();
    #pragma unroll
    for (int ii = 0; ii < 4; ++ii) {
        int i = i_sub * 4 + ii;
        float dtot = sh_den[0][o_h][i] + sh_den[1][o_h][i];
        float r = 1.0f / dtot;
        float4 o;
        o.x = num[ii][0] * r;
        o.y = num[ii][1] * r;
        o.z = num[ii][2] * r;
        o.w = num[ii][3] * r;
        *(float4*)(out + (size_t)(b * Ndim + i_base + i) * HD + c4 * 4) = o;
    }
}

extern "C" void kernel_launch(void* const* d_in, const int* in_sizes, int n_in,
                              void* d_out, int out_size, void* d_ws, size_t ws_size,
                              hipStream_t stream) {
    const float* x    = (const float*)d_in[0];
    const int*   adj  = (const int*)d_in[1];
    const float* W    = (const float*)d_in[2];
    const float* bias = (const float*)d_in[3];
    const float* a    = (const float*)d_in[4];
    float* out = (float*)d_out;

    float* ws = (float*)d_ws;
    float* h  = ws;                                   // 16384*128 f32 = 8 MB
    float* ei = ws + (size_t)Bdim * Ndim * HD;        // 64K f32
    float* ej = ei + (size_t)Bdim * Ndim * Hh;        // 64K f32

    proj_kernel<<<dim3((Bdim * Ndim) / 16), dim3(256), 0, stream>>>(
        x, W, bias, a, h, ei, ej);

    dim3 grid(Ndim / TI, Bdim);
    gat_kernel<<<grid, dim3(256), 0, stream>>>(adj, h, ei, ej, out);
}